// Round 5
// baseline (2388.443 us; speedup 1.0000x reference)
//
#include <hip/hip_runtime.h>
#include <hip/hip_bf16.h>
#include <math.h>

#define T_   4
#define B_   32
#define C_   384
#define N_   196
#define HID_ 1536
#define NH_  12
#define DH_  32
#define NCOL (B_*N_)            // 6272 columns (b,n)
#define XBLK 25                 // ceil(6272/256)

typedef unsigned char u8;

// ---------------------------------------------------------------------------
// Fused 1x1-conv + BN + LIF scan. f32 tensors in, all pre-threshold math in
// f64 so spike decisions match the f64 numpy reference (order noise ~1e-14
// vs >=1e-5 threshold gaps implied by jax-f32/np agreement).
// IN_MODE: 0 = f32 X; 1 = u8 X (spikes); 2 = f32 X + u8 Sadd (x + proj spikes)
// OM:      0 = write u8 spikes; 1 = write f32 (xres + sres + spike)  [final]
// NZ:      3 = fused q/k/v (z selects branch), else 1.
// Each thread owns one column (b,n), 8 output channels, all 4 timesteps.
// grid.x = XBLK * ny * NZ, xblk-major so same-column blocks are adjacent
// (shared X slice -> L2 locality).
// ---------------------------------------------------------------------------
template<int IN_MODE, int OM, int NZ>
__global__ __launch_bounds__(256) void conv_lif_kernel(
    const void* __restrict__ Xv, const u8* __restrict__ Sadd,
    const float* __restrict__ W0, const float* __restrict__ W1, const float* __restrict__ W2,
    const float* __restrict__ cb0, const float* __restrict__ cb1, const float* __restrict__ cb2,
    const float* __restrict__ bn0, const float* __restrict__ bn1, const float* __restrict__ bn2,
    const float* __restrict__ lw0, const float* __restrict__ lw1, const float* __restrict__ lw2,
    u8* S0, u8* S1, u8* S2,
    const float* __restrict__ xres, const u8* __restrict__ sres,
    float* out,
    int c_out, int c_in, int ny)
{
    __shared__ double w_lds[8][128];    // 8 KB
    const int tid = threadIdx.x;
    const int id  = blockIdx.x;
    const int xblk = id / (ny * NZ);
    const int rem  = id % (ny * NZ);
    const int z = (NZ == 1) ? 0 : (rem % NZ);
    const int y = (NZ == 1) ? rem : (rem / NZ);

    const float* W   = (z == 0) ? W0  : ((z == 1) ? W1  : W2);
    const float* cb  = (z == 0) ? cb0 : ((z == 1) ? cb1 : cb2);
    const float* bnp = (z == 0) ? bn0 : ((z == 1) ? bn1 : bn2);
    const float* lw  = (z == 0) ? lw0 : ((z == 1) ? lw1 : lw2);
    u8* SOUT         = (z == 0) ? S0  : ((z == 1) ? S1  : S2);

    const float* Xf = (const float*)Xv;
    const u8*    Xb = (const u8*)Xv;

    int col = xblk * 256 + tid;
    const bool valid = (col < NCOL);
    if (!valid) col = 0;
    const int b = col / N_, n = col % N_;
    const int o_base = y * 8;

    size_t xbase[4];
#pragma unroll
    for (int t = 0; t < 4; ++t)
        xbase[t] = ((size_t)(t * B_ + b) * c_in) * N_ + n;

    double acc[4][8];
#pragma unroll
    for (int t = 0; t < 4; ++t)
#pragma unroll
        for (int o = 0; o < 8; ++o) acc[t][o] = 0.0;

    for (int kc = 0; kc < c_in; kc += 128) {
        __syncthreads();
        // stage 8x128 W tile as f64: 256 threads x 1 float4 each
        {
            int o = tid >> 5;              // 0..7
            int k = (tid & 31) << 2;       // 0..124
            float4 w = *(const float4*)&W[(size_t)(o_base + o) * c_in + kc + k];
            w_lds[o][k    ] = (double)w.x;
            w_lds[o][k + 1] = (double)w.y;
            w_lds[o][k + 2] = (double)w.z;
            w_lds[o][k + 3] = (double)w.w;
        }
        __syncthreads();

#pragma unroll 2
        for (int k = 0; k < 128; k += 4) {
            double xv[4][4];
#pragma unroll
            for (int t = 0; t < 4; ++t)
#pragma unroll
                for (int kk = 0; kk < 4; ++kk) {
                    const size_t i = xbase[t] + (size_t)(kc + k + kk) * N_;
                    if (IN_MODE == 0)      xv[t][kk] = (double)Xf[i];
                    else if (IN_MODE == 1) xv[t][kk] = (double)Xb[i];
                    else                   xv[t][kk] = (double)Xf[i] + (double)Sadd[i];
                }
#pragma unroll
            for (int o = 0; o < 8; ++o) {
                const double w0 = w_lds[o][k];
                const double w1 = w_lds[o][k + 1];
                const double w2 = w_lds[o][k + 2];
                const double w3 = w_lds[o][k + 3];
#pragma unroll
                for (int t = 0; t < 4; ++t) {
                    acc[t][o] = fma(w0, xv[t][0], acc[t][o]);
                    acc[t][o] = fma(w1, xv[t][1], acc[t][o]);
                    acc[t][o] = fma(w2, xv[t][2], acc[t][o]);
                    acc[t][o] = fma(w3, xv[t][3], acc[t][o]);
                }
            }
        }
    }

    if (valid) {
        const double tau = 1.0 / (1.0 + exp(-(double)lw[0]));
        const size_t per_t = (size_t)B_ * c_out * N_;
#pragma unroll
        for (int o = 0; o < 8; ++o) {
            const int oo = o_base + o;
            const double g  = (double)bnp[oo];
            const double be = (double)bnp[c_out + oo];
            const double mm = (double)bnp[2 * c_out + oo];
            const double vv = (double)bnp[3 * c_out + oo];
            const double inv   = g / sqrt(vv + 1e-5);
            const double shift = be - mm * inv;
            const double cbv   = cb ? (double)cb[oo] : 0.0;
            const size_t idx0 = ((size_t)b * c_out + oo) * N_ + n;
            double v = 0.0;
#pragma unroll
            for (int t = 0; t < 4; ++t) {
                const double yv = (acc[t][o] + cbv) * inv + shift;
                const double h  = v + (yv - v) * tau;
                const double sp = (h >= 1.0) ? 1.0 : 0.0;
                v = h * (1.0 - sp);
                const size_t idx = (size_t)t * per_t + idx0;
                if (OM == 0) {
                    SOUT[idx] = (u8)sp;
                } else {
                    out[idx] = (float)((double)xres[idx] + (double)sres[idx] + sp);
                }
            }
        }
    }
}

// ---------------------------------------------------------------------------
// Spike attention + fused LIF. One block per (b,h); loops t internally.
// All values are dyadic rationals (ints scaled by 2^-k, k<=7, magnitude<2^13)
// -> exact in f32, bit-identical to any higher-precision reference.
// grid = B*NH = 384, block = 256
// ---------------------------------------------------------------------------
__global__ __launch_bounds__(256) void attn_lif_kernel(
    const u8* __restrict__ SQ, const u8* __restrict__ SK, const u8* __restrict__ SV,
    u8* __restrict__ SATT, const float* __restrict__ lw)
{
    __shared__ u8 q_lds[DH_ * N_];        // 6272 B
    __shared__ u8 k_lds[DH_ * N_];
    __shared__ u8 v_lds[DH_ * N_];
    __shared__ float kv_lds[DH_ * DH_];   // 4 KB
    __shared__ float vstate[DH_ * N_];    // 25 KB
    const int tid = threadIdx.x;
    const int b = blockIdx.x / NH_, h = blockIdx.x % NH_;
    const float tau = 1.0f / (1.0f + expf(-lw[0]));   // lw=0 -> exactly 0.5

    for (int i = tid; i < DH_ * N_; i += 256) vstate[i] = 0.0f;

    for (int t = 0; t < T_; ++t) {
        const size_t base = ((size_t)((t * B_ + b) * C_) + h * DH_) * N_;
        __syncthreads();
        for (int i = tid; i < DH_ * N_ / 4; i += 256) {
            ((unsigned int*)q_lds)[i] = ((const unsigned int*)(SQ + base))[i];
            ((unsigned int*)k_lds)[i] = ((const unsigned int*)(SK + base))[i];
            ((unsigned int*)v_lds)[i] = ((const unsigned int*)(SV + base))[i];
        }
        __syncthreads();

#pragma unroll
        for (int r = 0; r < 4; ++r) {
            const int e = tid + 256 * r;
            const int i = e >> 5, j = e & 31;
            int s = 0;
            for (int nn = 0; nn < N_; nn += 4) {
                uchar4 kk = *(const uchar4*)&k_lds[i * N_ + nn];
                uchar4 uv = *(const uchar4*)&v_lds[j * N_ + nn];
                s += kk.x * uv.x + kk.y * uv.y + kk.z * uv.z + kk.w * uv.w;
            }
            kv_lds[e] = (float)s;
        }
        __syncthreads();

        for (int e = tid; e < DH_ * N_; e += 256) {
            const int j = e / N_, nn = e % N_;
            float s = 0.0f;
#pragma unroll
            for (int i = 0; i < DH_; ++i)
                s += q_lds[i * N_ + nn] ? kv_lds[i * DH_ + j] : 0.0f;
            const float att = 0.125f * s;           // exact dyadic
            const float v = vstate[e];
            const float hh = v + (att - v) * tau;   // exact dyadic
            const float sp = (hh >= 1.0f) ? 1.0f : 0.0f;
            vstate[e] = hh * (1.0f - sp);
            SATT[base + e] = (u8)sp;
        }
    }
}

// ---------------------------------------------------------------------------
extern "C" void kernel_launch(void* const* d_in, const int* in_sizes, int n_in,
                              void* d_out, int out_size, void* d_ws, size_t ws_size,
                              hipStream_t stream)
{
    const float* x       = (const float*)d_in[0];
    const float* q_w     = (const float*)d_in[1];
    const float* q_bn    = (const float*)d_in[2];
    const float* q_lw    = (const float*)d_in[3];
    const float* k_w     = (const float*)d_in[4];
    const float* k_bn    = (const float*)d_in[5];
    const float* k_lw    = (const float*)d_in[6];
    const float* v_w     = (const float*)d_in[7];
    const float* v_bn    = (const float*)d_in[8];
    const float* v_lw    = (const float*)d_in[9];
    const float* attn_lw = (const float*)d_in[10];
    const float* proj_w  = (const float*)d_in[11];
    const float* proj_b  = (const float*)d_in[12];
    const float* proj_bn = (const float*)d_in[13];
    const float* proj_lw = (const float*)d_in[14];
    const float* fc1_w   = (const float*)d_in[15];
    const float* fc1_b   = (const float*)d_in[16];
    const float* fc1_bn  = (const float*)d_in[17];
    const float* fc1_lw  = (const float*)d_in[18];
    const float* fc2_w   = (const float*)d_in[19];
    const float* fc2_b   = (const float*)d_in[20];
    const float* fc2_bn  = (const float*)d_in[21];
    const float* fc2_lw  = (const float*)d_in[22];

    // ---- workspace: u8 spike tensors only (~83 MB, proven safe in r2-r4) ----
    u8* SQ   = (u8*)d_ws;                 // 9,633,792 B each
    u8* SK   = SQ + 9633792;
    u8* SV   = SK + 9633792;
    u8* SATT = SV + 9633792;
    u8* SP   = SATT + 9633792;            // proj spikes
    u8* SZ   = SP + 9633792;              // fc1 spikes, 38,535,168 B
    float* out = (float*)d_out;

    // 1. fused q/k/v conv+BN+LIF -> u8 spikes   (ny = 384/8 = 48)
    conv_lif_kernel<0, 0, 3><<<XBLK * 48 * 3, 256, 0, stream>>>(
        x, nullptr,
        q_w, k_w, v_w,
        nullptr, nullptr, nullptr,
        q_bn, k_bn, v_bn,
        q_lw, k_lw, v_lw,
        SQ, SK, SV,
        nullptr, nullptr, nullptr,
        C_, C_, 48);

    // 2. attention + LIF -> u8 spikes (exact arithmetic)
    attn_lif_kernel<<<B_ * NH_, 256, 0, stream>>>(SQ, SK, SV, SATT, attn_lw);

    // 3. proj conv + BN + LIF -> u8 spikes
    conv_lif_kernel<1, 0, 1><<<XBLK * 48, 256, 0, stream>>>(
        SATT, nullptr,
        proj_w, proj_w, proj_w,
        proj_b, proj_b, proj_b,
        proj_bn, proj_bn, proj_bn,
        proj_lw, proj_lw, proj_lw,
        SP, SP, SP,
        nullptr, nullptr, nullptr,
        C_, C_, 48);

    // 4. fc1 conv (input = f32 x + u8 SP, exact in f64) + BN + LIF -> spikes
    conv_lif_kernel<2, 0, 1><<<XBLK * 192, 256, 0, stream>>>(
        x, SP,
        fc1_w, fc1_w, fc1_w,
        fc1_b, fc1_b, fc1_b,
        fc1_bn, fc1_bn, fc1_bn,
        fc1_lw, fc1_lw, fc1_lw,
        SZ, SZ, SZ,
        nullptr, nullptr, nullptr,
        HID_, C_, 192);

    // 5. fc2 conv + BN + LIF + residual(x + SP) -> final f32 output
    conv_lif_kernel<1, 1, 1><<<XBLK * 48, 256, 0, stream>>>(
        SZ, nullptr,
        fc2_w, fc2_w, fc2_w,
        fc2_b, fc2_b, fc2_b,
        fc2_bn, fc2_bn, fc2_bn,
        fc2_lw, fc2_lw, fc2_lw,
        nullptr, nullptr, nullptr,
        x, SP, out,
        C_, HID_, 48);
}